// Round 1
// baseline (663.514 us; speedup 1.0000x reference)
//
#include <hip/hip_runtime.h>
#include <math.h>

#define HEADS 8
#define DK 64
#define DMODEL 512
#define BATCH 2
#define SEQ 2048

// ---------------------------------------------------------------------------
// Generic 64x64-tile f32 GEMM: Y = X(M x 512) @ W(512 x 512) + bias
// OUT_HEADS=1: write Y in [B, H, S, DK] layout (head-split)
// OUT_HEADS=0: write Y flat [M, 512]
// ---------------------------------------------------------------------------
template <int OUT_HEADS>
__global__ __launch_bounds__(256) void gemm512_kernel(
    const float* __restrict__ X, const float* __restrict__ W,
    const float* __restrict__ bias, float* __restrict__ Y) {
  __shared__ float As[16][65];  // A^T tile: As[k][m]
  __shared__ float Bs[16][64];  // B tile:   Bs[k][n]
  const int tid = threadIdx.x;
  const int tx = tid & 15, ty = tid >> 4;
  const int m0 = blockIdx.x * 64;  // 64 tiles over M=4096
  const int n0 = blockIdx.y * 64;  // 8 tiles over N=512

  float acc[4][4] = {};
  for (int k0 = 0; k0 < 512; k0 += 16) {
    #pragma unroll
    for (int e = 0; e < 4; ++e) {  // A tile 64x16
      int flat = tid + e * 256;
      int m = flat >> 4, k = flat & 15;
      As[k][m] = X[(size_t)(m0 + m) * 512 + k0 + k];
    }
    #pragma unroll
    for (int e = 0; e < 4; ++e) {  // B tile 16x64
      int flat = tid + e * 256;
      int k = flat >> 6, n = flat & 63;
      Bs[k][n] = W[(size_t)(k0 + k) * 512 + n0 + n];
    }
    __syncthreads();
    #pragma unroll
    for (int kk = 0; kk < 16; ++kk) {
      float a[4], b[4];
      #pragma unroll
      for (int i = 0; i < 4; ++i) a[i] = As[kk][ty + 16 * i];
      #pragma unroll
      for (int j = 0; j < 4; ++j) b[j] = Bs[kk][tx + 16 * j];
      #pragma unroll
      for (int i = 0; i < 4; ++i)
        #pragma unroll
        for (int j = 0; j < 4; ++j) acc[i][j] += a[i] * b[j];
    }
    __syncthreads();
  }
  #pragma unroll
  for (int i = 0; i < 4; ++i) {
    int m = m0 + ty + 16 * i;       // row in [0, 4096)
    int b = m >> 11, s = m & 2047;  // batch, seq
    #pragma unroll
    for (int j = 0; j < 4; ++j) {
      int n = n0 + tx + 16 * j;  // col in [0, 512)
      float v = acc[i][j] + bias[n];
      if (OUT_HEADS) {
        int h = n >> 6, d = n & 63;
        Y[(((size_t)(b * HEADS + h) * SEQ) + s) * DK + d] = v;
      } else {
        Y[(size_t)m * DMODEL + n] = v;
      }
    }
  }
}

// ---------------------------------------------------------------------------
// Scores: per (b,h) compute S = Qh @ Kh^T / 8, apply mask, write into attn buf
// ---------------------------------------------------------------------------
__global__ __launch_bounds__(256) void scores_kernel(
    const float* __restrict__ Qh, const float* __restrict__ Kh,
    const int* __restrict__ mask, float* __restrict__ attn) {
  __shared__ float Qs[64][65];
  __shared__ float Ks[64][65];
  const int bh = blockIdx.z;
  const int b = bh / HEADS;
  const int q0 = blockIdx.x * 64, k0 = blockIdx.y * 64;
  const float* Qb = Qh + (size_t)bh * SEQ * DK;
  const float* Kb = Kh + (size_t)bh * SEQ * DK;
  const int tid = threadIdx.x;
  const int tx = tid & 15, ty = tid >> 4;

  #pragma unroll
  for (int e = 0; e < 16; ++e) {  // 64x64 tiles, 4096 elems / 256 thr
    int flat = tid + e * 256;
    int r = flat >> 6, d = flat & 63;
    Qs[r][d] = Qb[(size_t)(q0 + r) * DK + d];
    Ks[r][d] = Kb[(size_t)(k0 + r) * DK + d];
  }
  __syncthreads();

  float acc[4][4] = {};
  #pragma unroll
  for (int kk = 0; kk < 64; ++kk) {
    float a[4], bv[4];
    #pragma unroll
    for (int i = 0; i < 4; ++i) a[i] = Qs[ty + 16 * i][kk];
    #pragma unroll
    for (int j = 0; j < 4; ++j) bv[j] = Ks[tx + 16 * j][kk];
    #pragma unroll
    for (int i = 0; i < 4; ++i)
      #pragma unroll
      for (int j = 0; j < 4; ++j) acc[i][j] += a[i] * bv[j];
  }

  const float scale = 0.125f;  // 1/sqrt(64)
  float* outp = attn + (size_t)bh * SEQ * SEQ;
  const int* mrow = mask + (size_t)b * SEQ * SEQ;
  #pragma unroll
  for (int i = 0; i < 4; ++i) {
    int q = q0 + ty + 16 * i;
    #pragma unroll
    for (int j = 0; j < 4; ++j) {
      int k = k0 + tx + 16 * j;
      float s = acc[i][j] * scale;
      if (mrow[(size_t)q * SEQ + k] == 0) s = -10000.0f;
      outp[(size_t)q * SEQ + k] = s;
    }
  }
}

// ---------------------------------------------------------------------------
// Row softmax, in place. One block (256 thr) per row of 2048.
// ---------------------------------------------------------------------------
__global__ __launch_bounds__(256) void softmax_kernel(float* __restrict__ attn) {
  const size_t row = blockIdx.x;
  float* p = attn + row * SEQ;
  const int tid = threadIdx.x;

  float vals[8];
  float m = -1e30f;
  #pragma unroll
  for (int e = 0; e < 8; ++e) {
    vals[e] = p[tid + e * 256];
    m = fmaxf(m, vals[e]);
  }
  #pragma unroll
  for (int o = 32; o > 0; o >>= 1) m = fmaxf(m, __shfl_xor(m, o));
  __shared__ float redm[4];
  if ((tid & 63) == 0) redm[tid >> 6] = m;
  __syncthreads();
  m = fmaxf(fmaxf(redm[0], redm[1]), fmaxf(redm[2], redm[3]));

  float sum = 0.f;
  #pragma unroll
  for (int e = 0; e < 8; ++e) {
    vals[e] = __expf(vals[e] - m);
    sum += vals[e];
  }
  #pragma unroll
  for (int o = 32; o > 0; o >>= 1) sum += __shfl_xor(sum, o);
  __shared__ float reds[4];
  if ((tid & 63) == 0) reds[tid >> 6] = sum;
  __syncthreads();
  sum = reds[0] + reds[1] + reds[2] + reds[3];

  const float inv = 1.0f / sum;
  #pragma unroll
  for (int e = 0; e < 8; ++e) p[tid + e * 256] = vals[e] * inv;
}

// ---------------------------------------------------------------------------
// PV: per (b,h) ctx = attn(2048x2048) @ Vh(2048x64); ctx written in concat
// layout [B, S, H*DK] so the output projection is a plain GEMM.
// ---------------------------------------------------------------------------
__global__ __launch_bounds__(256) void pv_kernel(
    const float* __restrict__ attn, const float* __restrict__ Vh,
    float* __restrict__ ctx) {
  __shared__ float As[16][65];  // attn^T tile
  __shared__ float Bs[16][64];  // V tile
  const int bh = blockIdx.z;
  const int b = bh / HEADS, h = bh % HEADS;
  const int m0 = blockIdx.x * 64;
  const float* A = attn + (size_t)bh * SEQ * SEQ;
  const float* V = Vh + (size_t)bh * SEQ * DK;
  const int tid = threadIdx.x;
  const int tx = tid & 15, ty = tid >> 4;

  float acc[4][4] = {};
  for (int k0 = 0; k0 < SEQ; k0 += 16) {
    #pragma unroll
    for (int e = 0; e < 4; ++e) {
      int flat = tid + e * 256;
      int m = flat >> 4, k = flat & 15;
      As[k][m] = A[(size_t)(m0 + m) * SEQ + k0 + k];
    }
    #pragma unroll
    for (int e = 0; e < 4; ++e) {
      int flat = tid + e * 256;
      int k = flat >> 6, n = flat & 63;
      Bs[k][n] = V[(size_t)(k0 + k) * DK + n];
    }
    __syncthreads();
    #pragma unroll
    for (int kk = 0; kk < 16; ++kk) {
      float a[4], bv[4];
      #pragma unroll
      for (int i = 0; i < 4; ++i) a[i] = As[kk][ty + 16 * i];
      #pragma unroll
      for (int j = 0; j < 4; ++j) bv[j] = Bs[kk][tx + 16 * j];
      #pragma unroll
      for (int i = 0; i < 4; ++i)
        #pragma unroll
        for (int j = 0; j < 4; ++j) acc[i][j] += a[i] * bv[j];
    }
    __syncthreads();
  }
  #pragma unroll
  for (int i = 0; i < 4; ++i) {
    int s = m0 + ty + 16 * i;
    #pragma unroll
    for (int j = 0; j < 4; ++j) {
      int d = tx + 16 * j;
      ctx[((size_t)(b * SEQ + s) * DMODEL) + h * DK + d] = acc[i][j];
    }
  }
}

// ---------------------------------------------------------------------------
extern "C" void kernel_launch(void* const* d_in, const int* in_sizes, int n_in,
                              void* d_out, int out_size, void* d_ws,
                              size_t ws_size, hipStream_t stream) {
  const float* q = (const float*)d_in[0];
  const float* k = (const float*)d_in[1];
  const float* v = (const float*)d_in[2];
  const int* mask = (const int*)d_in[3];
  const float* Wq = (const float*)d_in[4];
  const float* bq = (const float*)d_in[5];
  const float* Wk = (const float*)d_in[6];
  const float* bk = (const float*)d_in[7];
  const float* Wv = (const float*)d_in[8];
  const float* bv = (const float*)d_in[9];
  const float* Wo = (const float*)d_in[10];
  const float* bo = (const float*)d_in[11];

  float* out = (float*)d_out;                          // [B, S, DMODEL]
  float* attn = out + (size_t)BATCH * SEQ * DMODEL;    // [B, H, S, S]

  const size_t nh = (size_t)BATCH * HEADS * SEQ * DK;  // 2,097,152 floats
  float* Qh = (float*)d_ws;
  float* Kh = Qh + nh;
  float* Vh = Kh + nh;
  float* ctx = Qh;  // reuse Qh's slot after scores are computed

  dim3 blk(256);
  // projections -> head-split layout [B,H,S,DK]
  gemm512_kernel<1><<<dim3(64, 8), blk, 0, stream>>>(q, Wq, bq, Qh);
  gemm512_kernel<1><<<dim3(64, 8), blk, 0, stream>>>(k, Wk, bk, Kh);
  gemm512_kernel<1><<<dim3(64, 8), blk, 0, stream>>>(v, Wv, bv, Vh);
  // masked scores into attn region of d_out
  scores_kernel<<<dim3(32, 32, 16), blk, 0, stream>>>(Qh, Kh, mask, attn);
  // softmax in place (this IS the second output)
  softmax_kernel<<<dim3(BATCH * HEADS * SEQ), blk, 0, stream>>>(attn);
  // PV -> ctx in concat layout
  pv_kernel<<<dim3(32, 1, 16), blk, 0, stream>>>(attn, Vh, ctx);
  // output projection
  gemm512_kernel<0><<<dim3(64, 8), blk, 0, stream>>>(ctx, Wo, bo, out);
}

// Round 2
// 579.013 us; speedup vs baseline: 1.1459x; 1.1459x over previous
//
#include <hip/hip_runtime.h>
#include <math.h>

#define HEADS 8
#define DK 64
#define DMODEL 512
#define BATCH 2
#define SEQ 2048
#define BH (BATCH * HEADS)

using f32x4 = __attribute__((ext_vector_type(4))) float;
using s16x8 = __attribute__((ext_vector_type(8))) short;

union FragU {
  uint4 u;
  s16x8 s;
  unsigned short us[8];
};

__device__ __forceinline__ unsigned short f32_to_bf16(float f) {
  unsigned int u = __float_as_uint(f);
  u += 0x7fffu + ((u >> 16) & 1u);
  return (unsigned short)(u >> 16);
}
__device__ __forceinline__ float bf16_to_f32(unsigned short h) {
  return __uint_as_float(((unsigned int)h) << 16);
}

// ---------------------------------------------------------------------------
// f32 GEMM Y = X(4096 x 512) @ W(512 x 512) + bias.
// MODE 0: Y flat f32 (X = X1 + X2 summed on load, for ctx_a+ctx_b)
// MODE 1: head-split bf16 hi/lo pair  [BH][S][DK]
// MODE 2: head-split bf16             [BH][S][DK]
// ---------------------------------------------------------------------------
template <int MODE>
__global__ __launch_bounds__(256) void gemm512_kernel(
    const float* __restrict__ X, const float* __restrict__ X2,
    const float* __restrict__ W, const float* __restrict__ bias,
    float* __restrict__ Yf, unsigned short* __restrict__ Yhi,
    unsigned short* __restrict__ Ylo) {
  __shared__ float As[16][65];
  __shared__ float Bs[16][64];
  const int tid = threadIdx.x;
  const int tx = tid & 15, ty = tid >> 4;
  const int m0 = blockIdx.x * 64;
  const int n0 = blockIdx.y * 64;

  float acc[4][4] = {};
  for (int k0 = 0; k0 < 512; k0 += 16) {
    #pragma unroll
    for (int e = 0; e < 4; ++e) {
      int flat = tid + e * 256;
      int m = flat >> 4, k = flat & 15;
      size_t idx = (size_t)(m0 + m) * 512 + k0 + k;
      float xv = X[idx];
      if (MODE == 0) xv += X2[idx];
      As[k][m] = xv;
    }
    #pragma unroll
    for (int e = 0; e < 4; ++e) {
      int flat = tid + e * 256;
      int k = flat >> 6, n = flat & 63;
      Bs[k][n] = W[(size_t)(k0 + k) * 512 + n0 + n];
    }
    __syncthreads();
    #pragma unroll
    for (int kk = 0; kk < 16; ++kk) {
      float a[4], b[4];
      #pragma unroll
      for (int i = 0; i < 4; ++i) a[i] = As[kk][ty + 16 * i];
      #pragma unroll
      for (int j = 0; j < 4; ++j) b[j] = Bs[kk][tx + 16 * j];
      #pragma unroll
      for (int i = 0; i < 4; ++i)
        #pragma unroll
        for (int j = 0; j < 4; ++j) acc[i][j] += a[i] * b[j];
    }
    __syncthreads();
  }
  #pragma unroll
  for (int i = 0; i < 4; ++i) {
    int m = m0 + ty + 16 * i;
    int b = m >> 11, s = m & 2047;
    #pragma unroll
    for (int j = 0; j < 4; ++j) {
      int n = n0 + tx + 16 * j;
      float v = acc[i][j] + bias[n];
      if (MODE == 0) {
        Yf[(size_t)m * DMODEL + n] = v;
      } else {
        int h = n >> 6, d = n & 63;
        size_t idx = (((size_t)(b * HEADS + h) * SEQ) + s) * DK + d;
        unsigned short hi = f32_to_bf16(v);
        Yhi[idx] = hi;
        if (MODE == 1) Ylo[idx] = f32_to_bf16(v - bf16_to_f32(hi));
      }
    }
  }
}

// ---------------------------------------------------------------------------
// Vh[bh][s][d] bf16 -> Vt[bh][d][s] bf16
// ---------------------------------------------------------------------------
__global__ __launch_bounds__(256) void vtrans_kernel(
    const unsigned short* __restrict__ Vh, unsigned short* __restrict__ Vt) {
  __shared__ unsigned short t[64][72];
  const int tid = threadIdx.x;
  const int bh = blockIdx.y, s0 = blockIdx.x * 64;
  #pragma unroll
  for (int e = 0; e < 2; ++e) {
    int c = tid + e * 256;
    int r = c >> 3, c8 = (c & 7) * 8;
    *(uint4*)&t[r][c8] = *(const uint4*)&Vh[((size_t)bh * SEQ + s0 + r) * DK + c8];
  }
  __syncthreads();
  const int d = tid >> 2, sc0 = (tid & 3) * 16;
  #pragma unroll
  for (int e = 0; e < 16; ++e)
    Vt[((size_t)bh * DK + d) * SEQ + s0 + sc0 + e] = t[sc0 + e][d];
}

// ---------------------------------------------------------------------------
// Scores via split-bf16 MFMA. Block: 256 thr (4 waves), 64 q-rows x 256 k-cols
// (each wave owns a 64-col stripe). Writes masked scaled S into attn region
// and per-stripe softmax partials (m, l).
// MFMA frag maps (m89-verified): A: lane supplies A[l&15][(l>>4)*8+j];
// B: B[(l>>4)*8+j][l&15]; D: lane reg r holds D[(l>>4)*4+r][l&15].
// ---------------------------------------------------------------------------
__global__ __launch_bounds__(256, 4) void scores_kernel(
    const unsigned short* __restrict__ Qhi, const unsigned short* __restrict__ Qlo,
    const unsigned short* __restrict__ Khi, const unsigned short* __restrict__ Klo,
    const int* __restrict__ mask, float* __restrict__ attn,
    float* __restrict__ stats_part) {
  __shared__ unsigned short Qh_s[64 * 72];
  __shared__ unsigned short Ql_s[64 * 72];
  __shared__ float sm[4][64][2];

  const int bh = blockIdx.z, b = bh >> 3;
  const int q0 = blockIdx.x * 64;
  const int k0 = blockIdx.y * 256;
  const int tid = threadIdx.x;
  const int wv = tid >> 6, lane = tid & 63;
  const int lr = lane & 15, lg = lane >> 4;

  // stage Q hi/lo into padded LDS (stride 72 -> conflict-free b128 reads)
  const size_t qbase = ((size_t)bh * SEQ + q0) * DK;
  #pragma unroll
  for (int e = 0; e < 2; ++e) {
    int c = tid + e * 256;
    int r = c >> 3, c8 = (c & 7) * 8;
    *(uint4*)&Qh_s[r * 72 + c8] = *(const uint4*)&Qhi[qbase + r * DK + c8];
    *(uint4*)&Ql_s[r * 72 + c8] = *(const uint4*)&Qlo[qbase + r * DK + c8];
  }
  __syncthreads();

  f32x4 acc[4][4] = {};  // [i qtile][j ktile]
  const int kw = k0 + wv * 64;
  #pragma unroll
  for (int j = 0; j < 4; ++j) {
    #pragma unroll
    for (int dc = 0; dc < 2; ++dc) {
      const size_t kidx =
          ((size_t)bh * SEQ + kw + j * 16 + lr) * DK + dc * 32 + lg * 8;
      FragU kh, kl;
      kh.u = *(const uint4*)&Khi[kidx];
      kl.u = *(const uint4*)&Klo[kidx];
      #pragma unroll
      for (int i = 0; i < 4; ++i) {
        FragU qh, ql;
        const int qoff = (i * 16 + lr) * 72 + dc * 32 + lg * 8;
        qh.u = *(const uint4*)&Qh_s[qoff];
        ql.u = *(const uint4*)&Ql_s[qoff];
        acc[i][j] = __builtin_amdgcn_mfma_f32_16x16x32_bf16(qh.s, kh.s, acc[i][j], 0, 0, 0);
        acc[i][j] = __builtin_amdgcn_mfma_f32_16x16x32_bf16(qh.s, kl.s, acc[i][j], 0, 0, 0);
        acc[i][j] = __builtin_amdgcn_mfma_f32_16x16x32_bf16(ql.s, kh.s, acc[i][j], 0, 0, 0);
      }
    }
  }

  // scale + mask + store S
  #pragma unroll
  for (int i = 0; i < 4; ++i) {
    #pragma unroll
    for (int r = 0; r < 4; ++r) {
      const int q = q0 + i * 16 + lg * 4 + r;
      #pragma unroll
      for (int j = 0; j < 4; ++j) {
        const int kc = kw + j * 16 + lr;
        float s = acc[i][j][r] * 0.125f;
        if (mask[((size_t)b * SEQ + q) * SEQ + kc] == 0) s = -10000.0f;
        acc[i][j][r] = s;
        attn[((size_t)bh * SEQ + q) * SEQ + kc] = s;
      }
    }
  }

  // per-row (over this wave's 64 cols) max & sum-exp partials
  #pragma unroll
  for (int i = 0; i < 4; ++i) {
    #pragma unroll
    for (int r = 0; r < 4; ++r) {
      float mrow = fmaxf(fmaxf(acc[i][0][r], acc[i][1][r]),
                         fmaxf(acc[i][2][r], acc[i][3][r]));
      #pragma unroll
      for (int off = 1; off < 16; off <<= 1)
        mrow = fmaxf(mrow, __shfl_xor(mrow, off));
      float ls = 0.f;
      #pragma unroll
      for (int j = 0; j < 4; ++j) ls += __expf(acc[i][j][r] - mrow);
      #pragma unroll
      for (int off = 1; off < 16; off <<= 1) ls += __shfl_xor(ls, off);
      if (lr == 0) {
        sm[wv][i * 16 + lg * 4 + r][0] = mrow;
        sm[wv][i * 16 + lg * 4 + r][1] = ls;
      }
    }
  }
  __syncthreads();
  if (tid < 64) {
    float m = sm[0][tid][0];
    #pragma unroll
    for (int w = 1; w < 4; ++w) m = fmaxf(m, sm[w][tid][0]);
    float l = 0.f;
    #pragma unroll
    for (int w = 0; w < 4; ++w) l += sm[w][tid][1] * __expf(sm[w][tid][0] - m);
    const size_t o = ((size_t)bh * SEQ + q0 + tid) * 16 + (size_t)blockIdx.y * 2;
    stats_part[o] = m;
    stats_part[o + 1] = l;
  }
}

// ---------------------------------------------------------------------------
// Combine the 8 k-block partials per row -> (m, 1/l)
// ---------------------------------------------------------------------------
__global__ __launch_bounds__(256) void stats_reduce_kernel(
    const float* __restrict__ part, float* __restrict__ fin) {
  const int idx = blockIdx.x * 256 + threadIdx.x;  // bh*SEQ + q, 32768 total
  const float* p = part + (size_t)idx * 16;
  float m = p[0];
  #pragma unroll
  for (int i = 1; i < 8; ++i) m = fmaxf(m, p[i * 2]);
  float l = 0.f;
  #pragma unroll
  for (int i = 0; i < 8; ++i) l += p[i * 2 + 1] * __expf(p[i * 2] - m);
  fin[(size_t)idx * 2] = m;
  fin[(size_t)idx * 2 + 1] = 1.0f / l;
}

// ---------------------------------------------------------------------------
// Normalize S -> p (write back, = attn output) and PV via MFMA.
// Block: 512 thr (8 waves), q-tile 128 (16 rows/wave), k-half per blockIdx.y.
// ctx partial written to ctx + ks*4096*512 in concat layout [B,S,DMODEL].
// ---------------------------------------------------------------------------
__global__ __launch_bounds__(512) void pvnorm_kernel(
    float* __restrict__ attn, const float* __restrict__ statsf,
    const unsigned short* __restrict__ Vt, float* __restrict__ ctx) {
  const int bh = blockIdx.z, b = bh >> 3, h = bh & 7;
  const int ks = blockIdx.y;
  const int tid = threadIdx.x, wv = tid >> 6, lane = tid & 63;
  const int lr = lane & 15, lg = lane >> 4;
  const int qbase = blockIdx.x * 128 + wv * 16;

  float* Srow = attn + ((size_t)bh * SEQ + qbase + lr) * SEQ;
  const float mrow = statsf[((size_t)bh * SEQ + qbase + lr) * 2];
  const float invl = statsf[((size_t)bh * SEQ + qbase + lr) * 2 + 1];
  const unsigned short* Vb = Vt + (size_t)bh * DK * SEQ;
  float* C = ctx + (size_t)ks * (BATCH * SEQ * DMODEL);

  f32x4 acc[4] = {};
  for (int kc = ks * 32; kc < ks * 32 + 32; ++kc) {
    const int kk = kc * 32 + lg * 8;
    f32x4 s0 = *(const f32x4*)&Srow[kk];
    f32x4 s1 = *(const f32x4*)&Srow[kk + 4];
    f32x4 p0, p1;
    #pragma unroll
    for (int t = 0; t < 4; ++t) {
      p0[t] = __expf(s0[t] - mrow) * invl;
      p1[t] = __expf(s1[t] - mrow) * invl;
    }
    *(f32x4*)&Srow[kk] = p0;
    *(f32x4*)&Srow[kk + 4] = p1;
    FragU a;
    #pragma unroll
    for (int t = 0; t < 4; ++t) {
      a.us[t] = f32_to_bf16(p0[t]);
      a.us[4 + t] = f32_to_bf16(p1[t]);
    }
    #pragma unroll
    for (int dt = 0; dt < 4; ++dt) {
      FragU bv;
      bv.u = *(const uint4*)&Vb[(size_t)(dt * 16 + lr) * SEQ + kk];
      acc[dt] = __builtin_amdgcn_mfma_f32_16x16x32_bf16(a.s, bv.s, acc[dt], 0, 0, 0);
    }
  }
  #pragma unroll
  for (int dt = 0; dt < 4; ++dt)
    #pragma unroll
    for (int r = 0; r < 4; ++r)
      C[((size_t)(b * SEQ + qbase + lg * 4 + r)) * DMODEL + h * DK + dt * 16 + lr] =
          acc[dt][r];
}

// ---------------------------------------------------------------------------
extern "C" void kernel_launch(void* const* d_in, const int* in_sizes, int n_in,
                              void* d_out, int out_size, void* d_ws,
                              size_t ws_size, hipStream_t stream) {
  const float* q = (const float*)d_in[0];
  const float* k = (const float*)d_in[1];
  const float* v = (const float*)d_in[2];
  const int* mask = (const int*)d_in[3];
  const float* Wq = (const float*)d_in[4];
  const float* bq = (const float*)d_in[5];
  const float* Wk = (const float*)d_in[6];
  const float* bk = (const float*)d_in[7];
  const float* Wv = (const float*)d_in[8];
  const float* bv = (const float*)d_in[9];
  const float* Wo = (const float*)d_in[10];
  const float* bo = (const float*)d_in[11];

  float* out = (float*)d_out;
  float* attn = out + (size_t)BATCH * SEQ * DMODEL;

  char* w = (char*)d_ws;
  const size_t MB = 1u << 20;
  unsigned short* Qhi = (unsigned short*)(w + 0 * MB);
  unsigned short* Qlo = (unsigned short*)(w + 4 * MB);
  unsigned short* Khi = (unsigned short*)(w + 8 * MB);
  unsigned short* Klo = (unsigned short*)(w + 12 * MB);
  unsigned short* Vh16 = (unsigned short*)(w + 16 * MB);
  unsigned short* Vt = (unsigned short*)(w + 20 * MB);
  float* stats_part = (float*)(w + 24 * MB);  // [BH][S][8][2] = 2MB
  float* statsf = (float*)(w + 26 * MB);      // [BH][S][2]   = 0.5MB
  float* ctx_a = (float*)(w + 0 * MB);        // reuses Qhi/Qlo after scores
  float* ctx_b = (float*)(w + 8 * MB);        // reuses Khi/Klo

  dim3 blk(256);
  gemm512_kernel<1><<<dim3(64, 8), blk, 0, stream>>>(q, nullptr, Wq, bq, nullptr, Qhi, Qlo);
  gemm512_kernel<1><<<dim3(64, 8), blk, 0, stream>>>(k, nullptr, Wk, bk, nullptr, Khi, Klo);
  gemm512_kernel<2><<<dim3(64, 8), blk, 0, stream>>>(v, nullptr, Wv, bv, nullptr, Vh16, nullptr);
  vtrans_kernel<<<dim3(32, BH), blk, 0, stream>>>(Vh16, Vt);
  scores_kernel<<<dim3(32, 8, BH), blk, 0, stream>>>(Qhi, Qlo, Khi, Klo, mask, attn, stats_part);
  stats_reduce_kernel<<<dim3(128), blk, 0, stream>>>(stats_part, statsf);
  pvnorm_kernel<<<dim3(16, 2, BH), dim3(512), 0, stream>>>(attn, statsf, Vt, ctx_a);
  gemm512_kernel<0><<<dim3(64, 8), blk, 0, stream>>>(ctx_a, ctx_b, Wo, bo, out, nullptr, nullptr);
}

// Round 3
// 476.376 us; speedup vs baseline: 1.3928x; 1.2155x over previous
//
#include <hip/hip_runtime.h>
#include <math.h>

#define HEADS 8
#define DK 64
#define DMODEL 512
#define BATCH 2
#define SEQ 2048
#define BH (BATCH * HEADS)

using f32x4 = __attribute__((ext_vector_type(4))) float;
using s16x8 = __attribute__((ext_vector_type(8))) short;

union FragU {
  uint4 u;
  s16x8 s;
  unsigned short us[8];
};

__device__ __forceinline__ unsigned short f32_to_bf16(float f) {
  unsigned int u = __float_as_uint(f);
  u += 0x7fffu + ((u >> 16) & 1u);
  return (unsigned short)(u >> 16);
}
__device__ __forceinline__ float bf16_to_f32(unsigned short h) {
  return __uint_as_float(((unsigned int)h) << 16);
}

// ---------------------------------------------------------------------------
// mask int32 [B][S][S] -> packed bits [B][S][S/32]. One block per row.
// ---------------------------------------------------------------------------
__global__ __launch_bounds__(256) void pack_mask_kernel(
    const int* __restrict__ mask, unsigned int* __restrict__ bits) {
  const size_t row = blockIdx.x;  // B*S = 4096 rows
  const int wv = threadIdx.x >> 6, lane = threadIdx.x & 63;
  #pragma unroll
  for (int i = 0; i < 8; ++i) {
    const int c = wv * 512 + i * 64 + lane;
    unsigned long long bal = __ballot(mask[row * SEQ + c] != 0);
    if (lane == 0) {
      bits[row * 64 + (c >> 5)] = (unsigned int)bal;
      bits[row * 64 + (c >> 5) + 1] = (unsigned int)(bal >> 32);
    }
  }
}

// ---------------------------------------------------------------------------
// f32 GEMM Y = X(4096 x 512) @ W(512 x 512) + bias.
// MODE 1: head-split bf16 hi/lo pair [BH][S][DK]
// MODE 2: head-split bf16            [BH][S][DK]
// MODE 3: X is bf16 (u16), Y flat f32 [M][512]
// ---------------------------------------------------------------------------
template <int MODE>
__global__ __launch_bounds__(256) void gemm512_kernel(
    const float* __restrict__ X, const unsigned short* __restrict__ X16,
    const float* __restrict__ W, const float* __restrict__ bias,
    float* __restrict__ Yf, unsigned short* __restrict__ Yhi,
    unsigned short* __restrict__ Ylo) {
  __shared__ float As[16][65];
  __shared__ float Bs[16][64];
  const int tid = threadIdx.x;
  const int tx = tid & 15, ty = tid >> 4;
  const int m0 = blockIdx.x * 64;
  const int n0 = blockIdx.y * 64;

  float acc[4][4] = {};
  for (int k0 = 0; k0 < 512; k0 += 16) {
    #pragma unroll
    for (int e = 0; e < 4; ++e) {
      int flat = tid + e * 256;
      int m = flat >> 4, k = flat & 15;
      size_t idx = (size_t)(m0 + m) * 512 + k0 + k;
      As[k][m] = (MODE == 3) ? bf16_to_f32(X16[idx]) : X[idx];
    }
    #pragma unroll
    for (int e = 0; e < 4; ++e) {
      int flat = tid + e * 256;
      int k = flat >> 6, n = flat & 63;
      Bs[k][n] = W[(size_t)(k0 + k) * 512 + n0 + n];
    }
    __syncthreads();
    #pragma unroll
    for (int kk = 0; kk < 16; ++kk) {
      float a[4], b[4];
      #pragma unroll
      for (int i = 0; i < 4; ++i) a[i] = As[kk][ty + 16 * i];
      #pragma unroll
      for (int j = 0; j < 4; ++j) b[j] = Bs[kk][tx + 16 * j];
      #pragma unroll
      for (int i = 0; i < 4; ++i)
        #pragma unroll
        for (int j = 0; j < 4; ++j) acc[i][j] += a[i] * b[j];
    }
    __syncthreads();
  }
  #pragma unroll
  for (int i = 0; i < 4; ++i) {
    int m = m0 + ty + 16 * i;
    int b = m >> 11, s = m & 2047;
    #pragma unroll
    for (int j = 0; j < 4; ++j) {
      int n = n0 + tx + 16 * j;
      float v = acc[i][j] + bias[n];
      if (MODE == 3) {
        Yf[(size_t)m * DMODEL + n] = v;
      } else {
        int h = n >> 6, d = n & 63;
        size_t idx = (((size_t)(b * HEADS + h) * SEQ) + s) * DK + d;
        unsigned short hi = f32_to_bf16(v);
        Yhi[idx] = hi;
        if (MODE == 1) Ylo[idx] = f32_to_bf16(v - bf16_to_f32(hi));
      }
    }
  }
}

// ---------------------------------------------------------------------------
// Vh[bh][s][d] bf16 -> Vt[bh][d][s] bf16
// ---------------------------------------------------------------------------
__global__ __launch_bounds__(256) void vtrans_kernel(
    const unsigned short* __restrict__ Vh, unsigned short* __restrict__ Vt) {
  __shared__ unsigned short t[64][72];
  const int tid = threadIdx.x;
  const int bh = blockIdx.y, s0 = blockIdx.x * 64;
  #pragma unroll
  for (int e = 0; e < 2; ++e) {
    int c = tid + e * 256;
    int r = c >> 3, c8 = (c & 7) * 8;
    *(uint4*)&t[r][c8] = *(const uint4*)&Vh[((size_t)bh * SEQ + s0 + r) * DK + c8];
  }
  __syncthreads();
  const int d = tid >> 2, sc0 = (tid & 3) * 16;
  #pragma unroll
  for (int e = 0; e < 16; ++e)
    Vt[((size_t)bh * DK + d) * SEQ + s0 + sc0 + e] = t[sc0 + e][d];
}

// ---------------------------------------------------------------------------
// K1: split-bf16 QK^T, masked via bitmask, per-row (m,l) partials.
// Block: 64 q-rows x 512 k-cols, 4 waves each owning a 128-col stripe.
// S kept entirely in registers (8 jt x 4 i x f32x4); no S write.
// MFMA maps (R2-verified): A[lr][lg*8+j]; B[lg*8+j][lr]; D[lg*4+r][lr].
// ---------------------------------------------------------------------------
__global__ __launch_bounds__(256) void stats_kernel(
    const unsigned short* __restrict__ Qhi, const unsigned short* __restrict__ Qlo,
    const unsigned short* __restrict__ Khi, const unsigned short* __restrict__ Klo,
    const unsigned int* __restrict__ bits, float* __restrict__ stats_part) {
  __shared__ unsigned short Qh_s[64 * 72];
  __shared__ unsigned short Ql_s[64 * 72];
  __shared__ float sm[4][64][2];
  const int bh = blockIdx.z, b = bh >> 3;
  const int q0 = blockIdx.x * 64, kb = blockIdx.y;
  const int tid = threadIdx.x;
  const int wv = tid >> 6, lane = tid & 63;
  const int lr = lane & 15, lg = lane >> 4;

  const size_t qbase = ((size_t)bh * SEQ + q0) * DK;
  #pragma unroll
  for (int e = 0; e < 2; ++e) {
    int c = tid + e * 256;
    int r = c >> 3, c8 = (c & 7) * 8;
    *(uint4*)&Qh_s[r * 72 + c8] = *(const uint4*)&Qhi[qbase + r * DK + c8];
    *(uint4*)&Ql_s[r * 72 + c8] = *(const uint4*)&Qlo[qbase + r * DK + c8];
  }
  __syncthreads();

  const int kw0 = kb * 512 + wv * 128;
  f32x4 s[8][4] = {};
  #pragma unroll
  for (int jt = 0; jt < 8; ++jt) {
    #pragma unroll
    for (int dc = 0; dc < 2; ++dc) {
      const size_t kidx =
          ((size_t)bh * SEQ + kw0 + jt * 16 + lr) * DK + dc * 32 + lg * 8;
      FragU kh, kl;
      kh.u = *(const uint4*)&Khi[kidx];
      kl.u = *(const uint4*)&Klo[kidx];
      #pragma unroll
      for (int i = 0; i < 4; ++i) {
        FragU qh, ql;
        const int qoff = (i * 16 + lr) * 72 + dc * 32 + lg * 8;
        qh.u = *(const uint4*)&Qh_s[qoff];
        ql.u = *(const uint4*)&Ql_s[qoff];
        s[jt][i] = __builtin_amdgcn_mfma_f32_16x16x32_bf16(qh.s, kh.s, s[jt][i], 0, 0, 0);
        s[jt][i] = __builtin_amdgcn_mfma_f32_16x16x32_bf16(qh.s, kl.s, s[jt][i], 0, 0, 0);
        s[jt][i] = __builtin_amdgcn_mfma_f32_16x16x32_bf16(ql.s, kh.s, s[jt][i], 0, 0, 0);
      }
    }
  }

  #pragma unroll
  for (int i = 0; i < 4; ++i) {
    #pragma unroll
    for (int r = 0; r < 4; ++r) {
      const int q = q0 + i * 16 + lg * 4 + r;
      const size_t base = ((size_t)b * SEQ + q) * 64 + (kw0 >> 5);
      float vals[8];
      #pragma unroll
      for (int jt = 0; jt < 8; ++jt) {
        const unsigned int w = bits[base + (jt >> 1)];
        const bool keep = (w >> (((jt & 1) << 4) + lr)) & 1;
        vals[jt] = keep ? s[jt][i][r] * 0.125f : -10000.0f;
      }
      float m = vals[0];
      #pragma unroll
      for (int jt = 1; jt < 8; ++jt) m = fmaxf(m, vals[jt]);
      #pragma unroll
      for (int off = 1; off < 16; off <<= 1) m = fmaxf(m, __shfl_xor(m, off));
      float l = 0.f;
      #pragma unroll
      for (int jt = 0; jt < 8; ++jt) l += __expf(vals[jt] - m);
      #pragma unroll
      for (int off = 1; off < 16; off <<= 1) l += __shfl_xor(l, off);
      if (lr == 0) {
        sm[wv][i * 16 + lg * 4 + r][0] = m;
        sm[wv][i * 16 + lg * 4 + r][1] = l;
      }
    }
  }
  __syncthreads();
  if (tid < 64) {
    float m = sm[0][tid][0];
    #pragma unroll
    for (int w = 1; w < 4; ++w) m = fmaxf(m, sm[w][tid][0]);
    float l = 0.f;
    #pragma unroll
    for (int w = 0; w < 4; ++w) l += sm[w][tid][1] * __expf(sm[w][tid][0] - m);
    const size_t o = ((size_t)bh * SEQ + q0 + tid) * 8 + (size_t)kb * 2;
    stats_part[o] = m;
    stats_part[o + 1] = l;
  }
}

// ---------------------------------------------------------------------------
// Combine 4 k-block partials per row -> (m, 1/l)
// ---------------------------------------------------------------------------
__global__ __launch_bounds__(256) void stats_reduce_kernel(
    const float* __restrict__ part, float* __restrict__ fin) {
  const int idx = blockIdx.x * 256 + threadIdx.x;  // 32768 rows
  const float* p = part + (size_t)idx * 8;
  float m = p[0];
  #pragma unroll
  for (int i = 1; i < 4; ++i) m = fmaxf(m, p[i * 2]);
  float l = 0.f;
  #pragma unroll
  for (int i = 0; i < 4; ++i) l += p[i * 2 + 1] * __expf(p[i * 2] - m);
  fin[(size_t)idx * 2] = m;
  fin[(size_t)idx * 2 + 1] = 1.0f / l;
}

// ---------------------------------------------------------------------------
// K3: recompute S (bit-identical MFMA order), write final p once, PV MFMA.
// Block: 512 thr / 8 waves, 128 q-rows (16 per wave), sweeps all 32 k-tiles.
// K hi/lo staged in LDS shared by all waves; p routed through per-wave LDS
// tile to convert D-layout (q=lg*4+r, k=lr) -> A-frag layout (q=lr, k=lg*8+j).
// ---------------------------------------------------------------------------
__global__ __launch_bounds__(512) void pv_fused_kernel(
    const unsigned short* __restrict__ Qhi, const unsigned short* __restrict__ Qlo,
    const unsigned short* __restrict__ Khi, const unsigned short* __restrict__ Klo,
    const unsigned int* __restrict__ bits, const float* __restrict__ statsf,
    const unsigned short* __restrict__ Vt, float* __restrict__ attn,
    unsigned short* __restrict__ ctx16) {
  __shared__ unsigned short Kh_s[64 * 72];
  __shared__ unsigned short Kl_s[64 * 72];
  __shared__ unsigned short pbuf[8][16 * 72];
  const int bh = blockIdx.y, b = bh >> 3, h = bh & 7;
  const int tid = threadIdx.x, wv = tid >> 6, lane = tid & 63;
  const int lr = lane & 15, lg = lane >> 4;
  const int qw = blockIdx.x * 128 + wv * 16;

  // Q frags in registers (A layout: q = lr)
  FragU qh[2], ql[2];
  #pragma unroll
  for (int dc = 0; dc < 2; ++dc) {
    const size_t qi = ((size_t)bh * SEQ + qw + lr) * DK + dc * 32 + lg * 8;
    qh[dc].u = *(const uint4*)&Qhi[qi];
    ql[dc].u = *(const uint4*)&Qlo[qi];
  }
  // per-row stats + bases (D-layout rows: q = qw + lg*4 + r)
  float mr[4], il[4];
  size_t wbase[4], abase[4];
  #pragma unroll
  for (int r = 0; r < 4; ++r) {
    const int q = qw + lg * 4 + r;
    mr[r] = statsf[((size_t)bh * SEQ + q) * 2];
    il[r] = statsf[((size_t)bh * SEQ + q) * 2 + 1];
    wbase[r] = ((size_t)b * SEQ + q) * 64;
    abase[r] = ((size_t)bh * SEQ + q) * SEQ;
  }
  unsigned short* pb = pbuf[wv];
  f32x4 acc[4] = {};

  for (int kt = 0; kt < 32; ++kt) {
    const int kbase = kt * 64;
    __syncthreads();
    {
      const int row = tid >> 3, seg = (tid & 7) * 8;
      const size_t gi = ((size_t)bh * SEQ + kbase + row) * DK + seg;
      *(uint4*)&Kh_s[row * 72 + seg] = *(const uint4*)&Khi[gi];
      *(uint4*)&Kl_s[row * 72 + seg] = *(const uint4*)&Klo[gi];
    }
    __syncthreads();
    #pragma unroll
    for (int jt = 0; jt < 4; ++jt) {
      f32x4 sa = {};
      #pragma unroll
      for (int dc = 0; dc < 2; ++dc) {
        FragU kh, kl;
        const int ko = (jt * 16 + lr) * 72 + dc * 32 + lg * 8;
        kh.u = *(const uint4*)&Kh_s[ko];
        kl.u = *(const uint4*)&Kl_s[ko];
        sa = __builtin_amdgcn_mfma_f32_16x16x32_bf16(qh[dc].s, kh.s, sa, 0, 0, 0);
        sa = __builtin_amdgcn_mfma_f32_16x16x32_bf16(qh[dc].s, kl.s, sa, 0, 0, 0);
        sa = __builtin_amdgcn_mfma_f32_16x16x32_bf16(ql[dc].s, kh.s, sa, 0, 0, 0);
      }
      #pragma unroll
      for (int r = 0; r < 4; ++r) {
        const unsigned int w = bits[wbase[r] + kt * 2 + (jt >> 1)];
        const bool keep = (w >> (((jt & 1) << 4) + lr)) & 1;
        const float sv = keep ? sa[r] * 0.125f : -10000.0f;
        const float p = __expf(sv - mr[r]) * il[r];
        attn[abase[r] + kbase + jt * 16 + lr] = p;
        pb[(lg * 4 + r) * 72 + jt * 16 + lr] = f32_to_bf16(p);
      }
    }
    // PV: A = p (q=lr, k=lg*8+j) from pbuf; B = V[k][d] from Vt[d][k]
    #pragma unroll
    for (int dc2 = 0; dc2 < 2; ++dc2) {
      FragU pa;
      pa.u = *(const uint4*)&pb[lr * 72 + dc2 * 32 + lg * 8];
      #pragma unroll
      for (int dt = 0; dt < 4; ++dt) {
        FragU bv;
        bv.u = *(const uint4*)&Vt[((size_t)bh * DK + dt * 16 + lr) * SEQ + kbase +
                                  dc2 * 32 + lg * 8];
        acc[dt] = __builtin_amdgcn_mfma_f32_16x16x32_bf16(pa.s, bv.s, acc[dt], 0, 0, 0);
      }
    }
  }
  #pragma unroll
  for (int dt = 0; dt < 4; ++dt)
    #pragma unroll
    for (int r = 0; r < 4; ++r) {
      const int q = qw + lg * 4 + r;
      ctx16[((size_t)(b * SEQ + q)) * DMODEL + h * DK + dt * 16 + lr] =
          f32_to_bf16(acc[dt][r]);
    }
}

// ---------------------------------------------------------------------------
extern "C" void kernel_launch(void* const* d_in, const int* in_sizes, int n_in,
                              void* d_out, int out_size, void* d_ws,
                              size_t ws_size, hipStream_t stream) {
  const float* q = (const float*)d_in[0];
  const float* k = (const float*)d_in[1];
  const float* v = (const float*)d_in[2];
  const int* mask = (const int*)d_in[3];
  const float* Wq = (const float*)d_in[4];
  const float* bq = (const float*)d_in[5];
  const float* Wk = (const float*)d_in[6];
  const float* bk = (const float*)d_in[7];
  const float* Wv = (const float*)d_in[8];
  const float* bv = (const float*)d_in[9];
  const float* Wo = (const float*)d_in[10];
  const float* bo = (const float*)d_in[11];

  float* out = (float*)d_out;
  float* attn = out + (size_t)BATCH * SEQ * DMODEL;

  char* w = (char*)d_ws;
  const size_t MB = 1u << 20;
  unsigned short* Qhi = (unsigned short*)(w + 0 * MB);
  unsigned short* Qlo = (unsigned short*)(w + 4 * MB);
  unsigned short* Khi = (unsigned short*)(w + 8 * MB);
  unsigned short* Klo = (unsigned short*)(w + 12 * MB);
  unsigned short* Vh16 = (unsigned short*)(w + 16 * MB);  // dead after vtrans
  unsigned short* Vt = (unsigned short*)(w + 20 * MB);
  unsigned int* bits = (unsigned int*)(w + 24 * MB);      // 1 MB
  float* stats_part = (float*)(w + 25 * MB);              // 1 MB
  float* statsf = (float*)(w + 26 * MB);                  // 256 KB
  unsigned short* ctx16 = (unsigned short*)(w + 16 * MB); // overlays Vh16

  dim3 blk(256);
  pack_mask_kernel<<<dim3(BATCH * SEQ), blk, 0, stream>>>(mask, bits);
  gemm512_kernel<1><<<dim3(64, 8), blk, 0, stream>>>(q, nullptr, Wq, bq, nullptr, Qhi, Qlo);
  gemm512_kernel<1><<<dim3(64, 8), blk, 0, stream>>>(k, nullptr, Wk, bk, nullptr, Khi, Klo);
  gemm512_kernel<2><<<dim3(64, 8), blk, 0, stream>>>(v, nullptr, Wv, bv, nullptr, Vh16, nullptr);
  vtrans_kernel<<<dim3(32, BH), blk, 0, stream>>>(Vh16, Vt);
  stats_kernel<<<dim3(32, 4, BH), blk, 0, stream>>>(Qhi, Qlo, Khi, Klo, bits, stats_part);
  stats_reduce_kernel<<<dim3(128), blk, 0, stream>>>(stats_part, statsf);
  pv_fused_kernel<<<dim3(16, BH), dim3(512), 0, stream>>>(Qhi, Qlo, Khi, Klo, bits,
                                                          statsf, Vt, attn, ctx16);
  gemm512_kernel<3><<<dim3(64, 8), blk, 0, stream>>>(nullptr, ctx16, Wo, bo, out, nullptr, nullptr);
}

// Round 4
// 445.331 us; speedup vs baseline: 1.4899x; 1.0697x over previous
//
#include <hip/hip_runtime.h>
#include <math.h>

#define HEADS 8
#define DK 64
#define DMODEL 512
#define BATCH 2
#define SEQ 2048
#define BH (BATCH * HEADS)

using f32x4 = __attribute__((ext_vector_type(4))) float;
using s16x8 = __attribute__((ext_vector_type(8))) short;

union FragU {
  uint4 u;
  s16x8 s;
  unsigned short us[8];
};

__device__ __forceinline__ unsigned short f32_to_bf16(float f) {
  unsigned int u = __float_as_uint(f);
  u += 0x7fffu + ((u >> 16) & 1u);
  return (unsigned short)(u >> 16);
}
__device__ __forceinline__ float bf16_to_f32(unsigned short h) {
  return __uint_as_float(((unsigned int)h) << 16);
}

// ---------------------------------------------------------------------------
// mask int32 [B][S][S] -> packed bits [B][S][S/32]. One block per row.
// ---------------------------------------------------------------------------
__global__ __launch_bounds__(256) void pack_mask_kernel(
    const int* __restrict__ mask, unsigned int* __restrict__ bits) {
  const size_t row = blockIdx.x;  // B*S = 4096 rows
  const int wv = threadIdx.x >> 6, lane = threadIdx.x & 63;
  #pragma unroll
  for (int i = 0; i < 8; ++i) {
    const int c = wv * 512 + i * 64 + lane;
    unsigned long long bal = __ballot(mask[row * SEQ + c] != 0);
    if (lane == 0) {
      bits[row * 64 + (c >> 5)] = (unsigned int)bal;
      bits[row * 64 + (c >> 5) + 1] = (unsigned int)(bal >> 32);
    }
  }
}

// ---------------------------------------------------------------------------
// W[512][512] f32 -> Wt hi/lo bf16 in [n][k] (transposed) layout.
// Grid (8,8): 64x64 tile via LDS transpose.
// ---------------------------------------------------------------------------
__global__ __launch_bounds__(256) void wsplit_kernel(
    const float* __restrict__ W, unsigned short* __restrict__ WtHi,
    unsigned short* __restrict__ WtLo) {
  __shared__ float t[64][65];
  const int k0 = blockIdx.x * 64, n0 = blockIdx.y * 64;
  const int tid = threadIdx.x;
  const int r = tid >> 2, c = (tid & 3) * 16;
  #pragma unroll
  for (int e = 0; e < 4; ++e) {
    f32x4 v = *(const f32x4*)&W[(size_t)(k0 + r) * DMODEL + n0 + c + e * 4];
    #pragma unroll
    for (int j = 0; j < 4; ++j) t[r][c + e * 4 + j] = v[j];
  }
  __syncthreads();
  // write Wt rows: n = n0 + (tid>>2), k-range k0 + (tid&3)*16 .. +15
  const int rn = tid >> 2, ck = (tid & 3) * 16;
  #pragma unroll
  for (int half = 0; half < 2; ++half) {
    FragU hi, lo;
    #pragma unroll
    for (int e = 0; e < 8; ++e) {
      float x = t[ck + half * 8 + e][rn];
      unsigned short h = f32_to_bf16(x);
      hi.us[e] = h;
      lo.us[e] = f32_to_bf16(x - bf16_to_f32(h));
    }
    const size_t o = (size_t)(n0 + rn) * DMODEL + k0 + ck + half * 8;
    *(uint4*)&WtHi[o] = hi.u;
    *(uint4*)&WtLo[o] = lo.u;
  }
}

// ---------------------------------------------------------------------------
// MFMA projection GEMM: Y(4096x512) = X(4096x512) @ W + bias, W given as
// transposed hi/lo bf16 Wt[n][k]. LDS-free; A-frags converted in-register.
// MODE 1: Y -> head-split bf16 hi/lo pair [BH][S][DK]
// MODE 2: Y -> head-split bf16            [BH][S][DK]
// MODE 3: X is bf16 (ctx), Y -> flat f32  [M][512]
// MFMA maps (R2/R3-verified): A[lr][lg*8+j]; B[lg*8+j][lr]; D[lg*4+r][lr].
// ---------------------------------------------------------------------------
template <int MODE>
__global__ __launch_bounds__(256) void proj_mfma_kernel(
    const float* __restrict__ X, const unsigned short* __restrict__ X16,
    const unsigned short* __restrict__ WtHi,
    const unsigned short* __restrict__ WtLo, const float* __restrict__ bias,
    float* __restrict__ Yf, unsigned short* __restrict__ Yhi,
    unsigned short* __restrict__ Ylo) {
  const int tid = threadIdx.x, wv = tid >> 6, lane = tid & 63;
  const int lr = lane & 15, lg = lane >> 4;
  const int m0 = blockIdx.x * 64 + wv * 16;  // wave's 16 output rows
  const int n0 = blockIdx.y * 64;            // block's 64 output cols

  f32x4 acc[4] = {};
  for (int k0 = 0; k0 < 512; k0 += 64) {
    FragU ah[2], al[2];
    #pragma unroll
    for (int dc = 0; dc < 2; ++dc) {
      const size_t xi = (size_t)(m0 + lr) * DMODEL + k0 + dc * 32 + lg * 8;
      if (MODE == 3) {
        ah[dc].u = *(const uint4*)&X16[xi];
      } else {
        f32x4 x0 = *(const f32x4*)&X[xi];
        f32x4 x1 = *(const f32x4*)&X[xi + 4];
        #pragma unroll
        for (int t = 0; t < 4; ++t) {
          unsigned short h0 = f32_to_bf16(x0[t]);
          unsigned short h1 = f32_to_bf16(x1[t]);
          ah[dc].us[t] = h0;
          ah[dc].us[4 + t] = h1;
          al[dc].us[t] = f32_to_bf16(x0[t] - bf16_to_f32(h0));
          al[dc].us[4 + t] = f32_to_bf16(x1[t] - bf16_to_f32(h1));
        }
      }
    }
    #pragma unroll
    for (int jt = 0; jt < 4; ++jt) {
      #pragma unroll
      for (int dc = 0; dc < 2; ++dc) {
        const size_t wi =
            (size_t)(n0 + jt * 16 + lr) * DMODEL + k0 + dc * 32 + lg * 8;
        FragU bh, bl;
        bh.u = *(const uint4*)&WtHi[wi];
        bl.u = *(const uint4*)&WtLo[wi];
        acc[jt] = __builtin_amdgcn_mfma_f32_16x16x32_bf16(ah[dc].s, bh.s, acc[jt], 0, 0, 0);
        acc[jt] = __builtin_amdgcn_mfma_f32_16x16x32_bf16(ah[dc].s, bl.s, acc[jt], 0, 0, 0);
        if (MODE != 3)
          acc[jt] = __builtin_amdgcn_mfma_f32_16x16x32_bf16(al[dc].s, bh.s, acc[jt], 0, 0, 0);
      }
    }
  }

  #pragma unroll
  for (int jt = 0; jt < 4; ++jt) {
    const int n = n0 + jt * 16 + lr;
    const float bi = bias[n];
    #pragma unroll
    for (int r = 0; r < 4; ++r) {
      const int m = m0 + lg * 4 + r;
      const float v = acc[jt][r] + bi;
      if (MODE == 3) {
        Yf[(size_t)m * DMODEL + n] = v;
      } else {
        const int b = m >> 11, s = m & 2047;
        const int h = n >> 6, d = n & 63;
        const size_t idx = (((size_t)(b * HEADS + h) * SEQ) + s) * DK + d;
        unsigned short hi = f32_to_bf16(v);
        Yhi[idx] = hi;
        if (MODE == 1) Ylo[idx] = f32_to_bf16(v - bf16_to_f32(hi));
      }
    }
  }
}

// ---------------------------------------------------------------------------
// Vh[bh][s][d] bf16 -> Vt[bh][d][s] bf16
// ---------------------------------------------------------------------------
__global__ __launch_bounds__(256) void vtrans_kernel(
    const unsigned short* __restrict__ Vh, unsigned short* __restrict__ Vt) {
  __shared__ unsigned short t[64][72];
  const int tid = threadIdx.x;
  const int bh = blockIdx.y, s0 = blockIdx.x * 64;
  #pragma unroll
  for (int e = 0; e < 2; ++e) {
    int c = tid + e * 256;
    int r = c >> 3, c8 = (c & 7) * 8;
    *(uint4*)&t[r][c8] = *(const uint4*)&Vh[((size_t)bh * SEQ + s0 + r) * DK + c8];
  }
  __syncthreads();
  const int d = tid >> 2, sc0 = (tid & 3) * 16;
  #pragma unroll
  for (int e = 0; e < 16; ++e)
    Vt[((size_t)bh * DK + d) * SEQ + s0 + sc0 + e] = t[sc0 + e][d];
}

// ---------------------------------------------------------------------------
// K1: split-bf16 QK^T, masked via bitmask, per-row (m,l) partials.
// Block: 64 q-rows x 512 k-cols, 4 waves each owning a 128-col stripe.
// ---------------------------------------------------------------------------
__global__ __launch_bounds__(256) void stats_kernel(
    const unsigned short* __restrict__ Qhi, const unsigned short* __restrict__ Qlo,
    const unsigned short* __restrict__ Khi, const unsigned short* __restrict__ Klo,
    const unsigned int* __restrict__ bits, float* __restrict__ stats_part) {
  __shared__ unsigned short Qh_s[64 * 72];
  __shared__ unsigned short Ql_s[64 * 72];
  __shared__ float sm[4][64][2];
  const int bh = blockIdx.z, b = bh >> 3;
  const int q0 = blockIdx.x * 64, kb = blockIdx.y;
  const int tid = threadIdx.x;
  const int wv = tid >> 6, lane = tid & 63;
  const int lr = lane & 15, lg = lane >> 4;

  const size_t qbase = ((size_t)bh * SEQ + q0) * DK;
  #pragma unroll
  for (int e = 0; e < 2; ++e) {
    int c = tid + e * 256;
    int r = c >> 3, c8 = (c & 7) * 8;
    *(uint4*)&Qh_s[r * 72 + c8] = *(const uint4*)&Qhi[qbase + r * DK + c8];
    *(uint4*)&Ql_s[r * 72 + c8] = *(const uint4*)&Qlo[qbase + r * DK + c8];
  }
  __syncthreads();

  const int kw0 = kb * 512 + wv * 128;
  f32x4 s[8][4] = {};
  #pragma unroll
  for (int jt = 0; jt < 8; ++jt) {
    #pragma unroll
    for (int dc = 0; dc < 2; ++dc) {
      const size_t kidx =
          ((size_t)bh * SEQ + kw0 + jt * 16 + lr) * DK + dc * 32 + lg * 8;
      FragU kh, kl;
      kh.u = *(const uint4*)&Khi[kidx];
      kl.u = *(const uint4*)&Klo[kidx];
      #pragma unroll
      for (int i = 0; i < 4; ++i) {
        FragU qh, ql;
        const int qoff = (i * 16 + lr) * 72 + dc * 32 + lg * 8;
        qh.u = *(const uint4*)&Qh_s[qoff];
        ql.u = *(const uint4*)&Ql_s[qoff];
        s[jt][i] = __builtin_amdgcn_mfma_f32_16x16x32_bf16(qh.s, kh.s, s[jt][i], 0, 0, 0);
        s[jt][i] = __builtin_amdgcn_mfma_f32_16x16x32_bf16(qh.s, kl.s, s[jt][i], 0, 0, 0);
        s[jt][i] = __builtin_amdgcn_mfma_f32_16x16x32_bf16(ql.s, kh.s, s[jt][i], 0, 0, 0);
      }
    }
  }

  #pragma unroll
  for (int i = 0; i < 4; ++i) {
    #pragma unroll
    for (int r = 0; r < 4; ++r) {
      const int q = q0 + i * 16 + lg * 4 + r;
      const size_t base = ((size_t)b * SEQ + q) * 64 + (kw0 >> 5);
      float vals[8];
      #pragma unroll
      for (int jt = 0; jt < 8; ++jt) {
        const unsigned int w = bits[base + (jt >> 1)];
        const bool keep = (w >> (((jt & 1) << 4) + lr)) & 1;
        vals[jt] = keep ? s[jt][i][r] * 0.125f : -10000.0f;
      }
      float m = vals[0];
      #pragma unroll
      for (int jt = 1; jt < 8; ++jt) m = fmaxf(m, vals[jt]);
      #pragma unroll
      for (int off = 1; off < 16; off <<= 1) m = fmaxf(m, __shfl_xor(m, off));
      float l = 0.f;
      #pragma unroll
      for (int jt = 0; jt < 8; ++jt) l += __expf(vals[jt] - m);
      #pragma unroll
      for (int off = 1; off < 16; off <<= 1) l += __shfl_xor(l, off);
      if (lr == 0) {
        sm[wv][i * 16 + lg * 4 + r][0] = m;
        sm[wv][i * 16 + lg * 4 + r][1] = l;
      }
    }
  }
  __syncthreads();
  if (tid < 64) {
    float m = sm[0][tid][0];
    #pragma unroll
    for (int w = 1; w < 4; ++w) m = fmaxf(m, sm[w][tid][0]);
    float l = 0.f;
    #pragma unroll
    for (int w = 0; w < 4; ++w) l += sm[w][tid][1] * __expf(sm[w][tid][0] - m);
    const size_t o = ((size_t)bh * SEQ + q0 + tid) * 8 + (size_t)kb * 2;
    stats_part[o] = m;
    stats_part[o + 1] = l;
  }
}

// ---------------------------------------------------------------------------
// Combine 4 k-block partials per row -> (m, 1/l)
// ---------------------------------------------------------------------------
__global__ __launch_bounds__(256) void stats_reduce_kernel(
    const float* __restrict__ part, float* __restrict__ fin) {
  const int idx = blockIdx.x * 256 + threadIdx.x;  // 32768 rows
  const float* p = part + (size_t)idx * 8;
  float m = p[0];
  #pragma unroll
  for (int i = 1; i < 4; ++i) m = fmaxf(m, p[i * 2]);
  float l = 0.f;
  #pragma unroll
  for (int i = 0; i < 4; ++i) l += p[i * 2 + 1] * __expf(p[i * 2] - m);
  fin[(size_t)idx * 2] = m;
  fin[(size_t)idx * 2 + 1] = 1.0f / l;
}

// ---------------------------------------------------------------------------
// K3: recompute S (bit-identical MFMA order), write final p once, PV MFMA.
// ---------------------------------------------------------------------------
__global__ __launch_bounds__(512) void pv_fused_kernel(
    const unsigned short* __restrict__ Qhi, const unsigned short* __restrict__ Qlo,
    const unsigned short* __restrict__ Khi, const unsigned short* __restrict__ Klo,
    const unsigned int* __restrict__ bits, const float* __restrict__ statsf,
    const unsigned short* __restrict__ Vt, float* __restrict__ attn,
    unsigned short* __restrict__ ctx16) {
  __shared__ unsigned short Kh_s[64 * 72];
  __shared__ unsigned short Kl_s[64 * 72];
  __shared__ unsigned short pbuf[8][16 * 72];
  const int bh = blockIdx.y, b = bh >> 3, h = bh & 7;
  const int tid = threadIdx.x, wv = tid >> 6, lane = tid & 63;
  const int lr = lane & 15, lg = lane >> 4;
  const int qw = blockIdx.x * 128 + wv * 16;

  FragU qh[2], ql[2];
  #pragma unroll
  for (int dc = 0; dc < 2; ++dc) {
    const size_t qi = ((size_t)bh * SEQ + qw + lr) * DK + dc * 32 + lg * 8;
    qh[dc].u = *(const uint4*)&Qhi[qi];
    ql[dc].u = *(const uint4*)&Qlo[qi];
  }
  float mr[4], il[4];
  size_t wbase[4], abase[4];
  #pragma unroll
  for (int r = 0; r < 4; ++r) {
    const int q = qw + lg * 4 + r;
    mr[r] = statsf[((size_t)bh * SEQ + q) * 2];
    il[r] = statsf[((size_t)bh * SEQ + q) * 2 + 1];
    wbase[r] = ((size_t)b * SEQ + q) * 64;
    abase[r] = ((size_t)bh * SEQ + q) * SEQ;
  }
  unsigned short* pb = pbuf[wv];
  f32x4 acc[4] = {};

  for (int kt = 0; kt < 32; ++kt) {
    const int kbase = kt * 64;
    __syncthreads();
    {
      const int row = tid >> 3, seg = (tid & 7) * 8;
      const size_t gi = ((size_t)bh * SEQ + kbase + row) * DK + seg;
      *(uint4*)&Kh_s[row * 72 + seg] = *(const uint4*)&Khi[gi];
      *(uint4*)&Kl_s[row * 72 + seg] = *(const uint4*)&Klo[gi];
    }
    __syncthreads();
    #pragma unroll
    for (int jt = 0; jt < 4; ++jt) {
      f32x4 sa = {};
      #pragma unroll
      for (int dc = 0; dc < 2; ++dc) {
        FragU kh, kl;
        const int ko = (jt * 16 + lr) * 72 + dc * 32 + lg * 8;
        kh.u = *(const uint4*)&Kh_s[ko];
        kl.u = *(const uint4*)&Kl_s[ko];
        sa = __builtin_amdgcn_mfma_f32_16x16x32_bf16(qh[dc].s, kh.s, sa, 0, 0, 0);
        sa = __builtin_amdgcn_mfma_f32_16x16x32_bf16(qh[dc].s, kl.s, sa, 0, 0, 0);
        sa = __builtin_amdgcn_mfma_f32_16x16x32_bf16(ql[dc].s, kh.s, sa, 0, 0, 0);
      }
      #pragma unroll
      for (int r = 0; r < 4; ++r) {
        const unsigned int w = bits[wbase[r] + kt * 2 + (jt >> 1)];
        const bool keep = (w >> (((jt & 1) << 4) + lr)) & 1;
        const float sv = keep ? sa[r] * 0.125f : -10000.0f;
        const float p = __expf(sv - mr[r]) * il[r];
        attn[abase[r] + kbase + jt * 16 + lr] = p;
        pb[(lg * 4 + r) * 72 + jt * 16 + lr] = f32_to_bf16(p);
      }
    }
    #pragma unroll
    for (int dc2 = 0; dc2 < 2; ++dc2) {
      FragU pa;
      pa.u = *(const uint4*)&pb[lr * 72 + dc2 * 32 + lg * 8];
      #pragma unroll
      for (int dt = 0; dt < 4; ++dt) {
        FragU bv;
        bv.u = *(const uint4*)&Vt[((size_t)bh * DK + dt * 16 + lr) * SEQ + kbase +
                                  dc2 * 32 + lg * 8];
        acc[dt] = __builtin_amdgcn_mfma_f32_16x16x32_bf16(pa.s, bv.s, acc[dt], 0, 0, 0);
      }
    }
  }
  #pragma unroll
  for (int dt = 0; dt < 4; ++dt)
    #pragma unroll
    for (int r = 0; r < 4; ++r) {
      const int q = qw + lg * 4 + r;
      ctx16[((size_t)(b * SEQ + q)) * DMODEL + h * DK + dt * 16 + lr] =
          f32_to_bf16(acc[dt][r]);
    }
}

// ---------------------------------------------------------------------------
extern "C" void kernel_launch(void* const* d_in, const int* in_sizes, int n_in,
                              void* d_out, int out_size, void* d_ws,
                              size_t ws_size, hipStream_t stream) {
  const float* q = (const float*)d_in[0];
  const float* k = (const float*)d_in[1];
  const float* v = (const float*)d_in[2];
  const int* mask = (const int*)d_in[3];
  const float* Wq = (const float*)d_in[4];
  const float* bq = (const float*)d_in[5];
  const float* Wk = (const float*)d_in[6];
  const float* bk = (const float*)d_in[7];
  const float* Wv = (const float*)d_in[8];
  const float* bv = (const float*)d_in[9];
  const float* Wo = (const float*)d_in[10];
  const float* bo = (const float*)d_in[11];

  float* out = (float*)d_out;
  float* attn = out + (size_t)BATCH * SEQ * DMODEL;

  char* w = (char*)d_ws;
  const size_t MB = 1u << 20;
  unsigned short* Qhi = (unsigned short*)(w + 0 * MB);
  unsigned short* Qlo = (unsigned short*)(w + 4 * MB);
  unsigned short* Khi = (unsigned short*)(w + 8 * MB);
  unsigned short* Klo = (unsigned short*)(w + 12 * MB);
  unsigned short* Vh16 = (unsigned short*)(w + 16 * MB);   // dead after vtrans
  unsigned short* Vt = (unsigned short*)(w + 20 * MB);
  unsigned int* bits = (unsigned int*)(w + 24 * MB);       // 1 MB
  float* stats_part = (float*)(w + 25 * MB);               // 1 MB
  float* statsf = (float*)(w + 26 * MB);                   // 256 KB
  unsigned short* WtHi = (unsigned short*)(w + 26 * MB + 256 * 1024);  // 512 KB
  unsigned short* WtLo = (unsigned short*)(w + 26 * MB + 768 * 1024);  // 512 KB
  unsigned short* ctx16 = (unsigned short*)(w + 16 * MB);  // overlays Vh16

  dim3 blk(256);
  pack_mask_kernel<<<dim3(BATCH * SEQ), blk, 0, stream>>>(mask, bits);

  wsplit_kernel<<<dim3(8, 8), blk, 0, stream>>>(Wq, WtHi, WtLo);
  proj_mfma_kernel<1><<<dim3(64, 8), blk, 0, stream>>>(q, nullptr, WtHi, WtLo, bq,
                                                       nullptr, Qhi, Qlo);
  wsplit_kernel<<<dim3(8, 8), blk, 0, stream>>>(Wk, WtHi, WtLo);
  proj_mfma_kernel<1><<<dim3(64, 8), blk, 0, stream>>>(k, nullptr, WtHi, WtLo, bk,
                                                       nullptr, Khi, Klo);
  wsplit_kernel<<<dim3(8, 8), blk, 0, stream>>>(Wv, WtHi, WtLo);
  proj_mfma_kernel<2><<<dim3(64, 8), blk, 0, stream>>>(v, nullptr, WtHi, WtLo, bv,
                                                       nullptr, Vh16, nullptr);
  vtrans_kernel<<<dim3(32, BH), blk, 0, stream>>>(Vh16, Vt);

  stats_kernel<<<dim3(32, 4, BH), blk, 0, stream>>>(Qhi, Qlo, Khi, Klo, bits, stats_part);
  stats_reduce_kernel<<<dim3(128), blk, 0, stream>>>(stats_part, statsf);
  pv_fused_kernel<<<dim3(16, BH), dim3(512), 0, stream>>>(Qhi, Qlo, Khi, Klo, bits,
                                                          statsf, Vt, attn, ctx16);

  wsplit_kernel<<<dim3(8, 8), blk, 0, stream>>>(Wo, WtHi, WtLo);
  proj_mfma_kernel<3><<<dim3(64, 8), blk, 0, stream>>>(nullptr, ctx16, WtHi, WtLo, bo,
                                                       out, nullptr, nullptr);
}